// Round 6
// baseline (435.071 us; speedup 1.0000x reference)
//
#include <hip/hip_runtime.h>
#include <math.h>

#define NZ    128
#define H1    512
#define H2    1024
#define IMG   784
#define IMGP  896     // layer-3 N padded to 7*128
#define BATCH 4096
#define NGEN  10
#define MPAD  128     // packed-row slack so tail tiles can stage past ng
#define NWORK 512     // persistent workers: 2 blocks/CU (64 KB LDS -> max 2/CU;
                      // 512 blocks == 256 CUs x 2 slots -> all co-resident)

typedef _Float16 f16;
typedef __attribute__((ext_vector_type(8))) _Float16 half8;
typedef __attribute__((ext_vector_type(4))) float floatx4;

// transpose tile counts (64x64 tiles)
#define TB1 ((NZ / 64) * (H1 / 64) * NGEN)    // 160
#define TB2 ((H1 / 64) * (H2 / 64) * NGEN)    // 1280
#define TB3 ((H2 / 64) * (IMGP / 64) * NGEN)  // 2240

__device__ __forceinline__ void cp16(void* l, const void* g) {
    __builtin_amdgcn_global_load_lds((const __attribute__((address_space(1))) void*)g,
                                     (__attribute__((address_space(3))) void*)l, 16, 0, 0);
}

// ---------------- grid barrier (all NWORK blocks co-resident by construction) ----
__device__ __forceinline__ void gridbar(int* bar, int phase) {
    __syncthreads();                          // block's stores drained to L2
    if (threadIdx.x == 0) {
        __threadfence();                      // belt & suspenders
        __hip_atomic_fetch_add(&bar[phase], 1, __ATOMIC_RELEASE,
                               __HIP_MEMORY_SCOPE_AGENT);
        while (__hip_atomic_load(&bar[phase], __ATOMIC_ACQUIRE,
                                 __HIP_MEMORY_SCOPE_AGENT) < NWORK)
            __builtin_amdgcn_s_sleep(8);
        __threadfence();
    }
    __syncthreads();
}

// ---------------- transpose one 64x64 tile: W [g][K][N] f32 -> Wt [g][NPAD][K] f16 --
template<int K, int N, int NPAD>
__device__ void t_item(int idx, const float* __restrict__ W,
                       f16* __restrict__ Wt, char* smraw) {
    f16 (*L)[72] = (f16(*)[72])smraw;         // 18 KB, inside the 64 KB union
    __syncthreads();                          // prior item's LDS reads done
    constexpr int KT = K / 64, NT = NPAD / 64;
    const int g  = idx / (KT * NT);
    const int r2 = idx % (KT * NT);
    const int k0 = (r2 % KT) * 64;
    const int n0 = (r2 / KT) * 64;
    const int t = threadIdx.x;
    {
        const int kk0 = t >> 4;               // 0..15
        const int nq  = (t & 15) * 4;         // 0..60
        #pragma unroll
        for (int it = 0; it < 4; ++it) {
            const int kk = kk0 + it * 16;
            float4 v = make_float4(0.f, 0.f, 0.f, 0.f);
            if (n0 + nq < N)                  // N % 4 == 0: quads never straddle
                v = *(const float4*)(W + ((size_t)g * K + (k0 + kk)) * N + n0 + nq);
            L[nq + 0][kk] = (f16)v.x;
            L[nq + 1][kk] = (f16)v.y;
            L[nq + 2][kk] = (f16)v.z;
            L[nq + 3][kk] = (f16)v.w;
        }
    }
    __syncthreads();
    {
        const int nn0 = t >> 3;               // 0..31
        const int kq  = (t & 7) * 8;          // 0..56
        #pragma unroll
        for (int it = 0; it < 2; ++it) {
            const int nn = nn0 + it * 32;
            *(half8*)(Wt + ((size_t)g * NPAD + (n0 + nn)) * K + k0 + kq) =
                *(const half8*)&L[nn][kq];
        }
    }
}

// ---------------- histogram + segment starts + permutation (one block) -----------
__device__ void hist_item(const int* __restrict__ g_idx, int* __restrict__ seg,
                          int* __restrict__ perm, char* smraw) {
    int* lc = (int*)smraw;                    // NGEN counters / cursors
    int* lb = lc + NGEN;                      // NGEN+1 bounds
    const int t = threadIdx.x;
    __syncthreads();
    if (t < NGEN) lc[t] = 0;
    __syncthreads();
    int gv[BATCH / 256];
    #pragma unroll
    for (int i = 0; i < BATCH / 256; ++i) {
        gv[i] = g_idx[t + i * 256];
        atomicAdd(&lc[gv[i]], 1);
    }
    __syncthreads();
    if (t == 0) {
        int s = 0;
        #pragma unroll
        for (int g = 0; g < NGEN; ++g) { lb[g] = s; s += lc[g]; }
        lb[NGEN] = s;
    }
    __syncthreads();
    if (t <= NGEN) seg[t] = lb[t];
    if (t < NGEN) lc[t] = lb[t];              // reuse as cursors
    __syncthreads();
    #pragma unroll
    for (int i = 0; i < BATCH / 256; ++i) {
        int p = atomicAdd(&lc[gv[i]], 1);
        perm[p] = t + i * 256;
    }
}

// ---------------- live-tile enumeration (adaptive m-tiling from seg) -------------
template<int NN>
__device__ __forceinline__ int live_total(const int* __restrict__ seg) {
    int s = 0;
    #pragma unroll
    for (int g = 0; g < NGEN; ++g)
        s += (((seg[g + 1] - seg[g]) + 127) >> 7) * NN;
    return s;
}
template<int NN>
__device__ __forceinline__ void item_to_tile(const int* __restrict__ seg, int i,
                                             int& g, int& s0, int& ng,
                                             int& m0, int& n0) {
    int base = 0;
    #pragma unroll
    for (int gg = 0; gg < NGEN; ++gg) {
        const int s = seg[gg], e = seg[gg + 1];
        const int cm = ((e - s) + 127) >> 7;
        const int c  = cm * NN;
        if (i >= base && i < base + c) {
            const int loc = i - base;
            g = gg; s0 = s; ng = e - s;
            m0 = (loc % cm) * 128;
            n0 = (loc / cm) * 128;
        }
        base += c;
    }
}

// ---------------- 128x128-tile GEMM item, counted-vmcnt double-buffer ------------
// 4 waves 2x2, each 64x64 (acc[4][4]); A/B via cp16, 8 each per 64-K tile.
// Per step: vmcnt(8) [tile k landed; tile k+1 stays in flight across the
// barrier] -> s_barrier -> 16 ds_read_b128 -> lgkmcnt(0) -> s_barrier#2
// [buffer free] -> stage tile k+2 -> 32 MFMA. No vmcnt(0) drain in-loop.
// Entry __syncthreads drains all counters -> vmcnt counting valid per item.
// LDS XOR-swizzle: phys k-quad = logical ^ ((row>>1)&7) (2-way = free).
template<int K, int NOUT, int NPADB, int ACT, int SCATTER>
__device__ void gemm_item(int g, int s0, int ng, int m0, int n0,
                          const f16* __restrict__ Ap, const f16* __restrict__ Wt,
                          const float* __restrict__ bias, f16* __restrict__ Ch,
                          float* __restrict__ Cout, const int* __restrict__ perm,
                          char* smraw) {
    constexpr int NT = K / 64;
    f16* As = (f16*)smraw;                    // [2][8192]
    f16* Bs = (f16*)(smraw + 32768);          // [2][8192]
    const int tid = threadIdx.x, lane = tid & 63, w = tid >> 6;

    __syncthreads();                          // LDS reusable + counters drained

    const f16* ga[4]; const f16* gb[4]; int lo[4];
    #pragma unroll
    for (int j = 0; j < 4; ++j) {
        const int r   = w * 32 + j * 8 + (lane >> 3);
        const int swz = ((lane & 7) ^ ((r >> 1) & 7)) * 8;
        ga[j] = Ap + (size_t)(s0 + m0 + r) * K + swz;
        gb[j] = Wt + ((size_t)g * NPADB + n0 + r) * K + swz;
        lo[j] = (w * 32 + j * 8) * 64;        // wave-uniform LDS base
    }
    const int wm = (w & 1) * 64, wn = (w >> 1) * 64;
    const int lm = lane & 15, lq = lane >> 4;

    const int c = n0 + wn + 2 * lm;
    const bool in0 = (!SCATTER) || (c < NOUT);
    const bool in1 = (!SCATTER) || (c + 32 < NOUT);
    const float* bg = bias + (size_t)g * NOUT;
    const float bv0 = in0 ? bg[c]      : 0.f;
    const float bv1 = in0 ? bg[c + 1]  : 0.f;
    const float bv2 = in1 ? bg[c + 32] : 0.f;
    const float bv3 = in1 ? bg[c + 33] : 0.f;

    floatx4 acc[4][4] = {};

    auto stage = [&](int t, int b) {
        #pragma unroll
        for (int j = 0; j < 4; ++j) cp16(&As[b * 8192 + lo[j]], ga[j] + (size_t)t * 64);
        #pragma unroll
        for (int j = 0; j < 4; ++j) cp16(&Bs[b * 8192 + lo[j]], gb[j] + (size_t)t * 64);
    };
    stage(0, 0);
    __builtin_amdgcn_sched_barrier(0);        // tile0's 8 loads strictly older
    stage(1, 1);

    for (int kc = 0; kc < NT; ++kc) {
        if (kc + 1 < NT) asm volatile("s_waitcnt vmcnt(8)" ::: "memory");
        else             asm volatile("s_waitcnt vmcnt(0)" ::: "memory");
        __builtin_amdgcn_sched_barrier(0);
        __builtin_amdgcn_s_barrier();         // tile kc visible to all waves
        __builtin_amdgcn_sched_barrier(0);

        const int cb = (kc & 1) * 8192;
        half8 a[2][4], b[2][4];
        #pragma unroll
        for (int ks = 0; ks < 2; ++ks) {
            #pragma unroll
            for (int mt = 0; mt < 4; ++mt) {
                const int r  = wm + mt * 16 + lm;
                const int pq = (ks * 4 + lq) ^ ((r >> 1) & 7);
                a[ks][mt] = *(const half8*)&As[cb + r * 64 + pq * 8];
            }
            #pragma unroll
            for (int nf = 0; nf < 4; ++nf) {
                const int r  = wn + (nf >> 1) * 32 + 2 * lm + (nf & 1);
                const int pq = (ks * 4 + lq) ^ ((r >> 1) & 7);
                b[ks][nf] = *(const half8*)&Bs[cb + r * 64 + pq * 8];
            }
        }
        asm volatile("s_waitcnt lgkmcnt(0)" ::: "memory");
        __builtin_amdgcn_sched_barrier(0);
        if (kc + 2 < NT) {
            __builtin_amdgcn_s_barrier();     // ALL waves' reads done: buf free
            __builtin_amdgcn_sched_barrier(0);
            stage(kc + 2, kc & 1);
        }
        #pragma unroll
        for (int ks = 0; ks < 2; ++ks)
            #pragma unroll
            for (int mt = 0; mt < 4; ++mt)
                #pragma unroll
                for (int nf = 0; nf < 4; ++nf)
                    acc[mt][nf] = __builtin_amdgcn_mfma_f32_16x16x32_f16(
                        a[ks][mt], b[ks][nf], acc[mt][nf], 0, 0, 0);
    }

    #pragma unroll
    for (int mt = 0; mt < 4; ++mt)
        #pragma unroll
        for (int rr = 0; rr < 4; ++rr) {
            const int gr = m0 + wm + mt * 16 + lq * 4 + rr;
            if (gr >= ng) continue;
            float x0 = acc[mt][0][rr] + bv0;
            float x1 = acc[mt][1][rr] + bv1;
            float x2 = acc[mt][2][rr] + bv2;
            float x3 = acc[mt][3][rr] + bv3;
            if (ACT == 0) {
                x0 = fmaxf(x0, 0.f); x1 = fmaxf(x1, 0.f);
                x2 = fmaxf(x2, 0.f); x3 = fmaxf(x3, 0.f);
            } else {                          // tanh, inf-safe
                const float e0 = __expf(2.f * x0);
                const float e1 = __expf(2.f * x1);
                const float e2 = __expf(2.f * x2);
                const float e3 = __expf(2.f * x3);
                x0 = 1.f - 2.f / (e0 + 1.f);
                x1 = 1.f - 2.f / (e1 + 1.f);
                x2 = 1.f - 2.f / (e2 + 1.f);
                x3 = 1.f - 2.f / (e3 + 1.f);
            }
            if (SCATTER) {
                const size_t orow = (size_t)perm[s0 + gr];
                if (in0) *(float2*)&Cout[orow * NOUT + c]      = make_float2(x0, x1);
                if (in1) *(float2*)&Cout[orow * NOUT + c + 32] = make_float2(x2, x3);
            } else {
                union { uint u; f16 h[2]; } o0, o1;
                o0.h[0] = (f16)x0; o0.h[1] = (f16)x1;
                o1.h[0] = (f16)x2; o1.h[1] = (f16)x3;
                *(uint*)&Ch[(size_t)(s0 + gr) * NOUT + c]      = o0.u;
                *(uint*)&Ch[(size_t)(s0 + gr) * NOUT + c + 32] = o1.u;
            }
        }
}

// ---------------- layer-1 item: K=128, both K-tiles staged up-front --------------
// A gathered from f32 z via perm (in-register convert, swizzled ds_write);
// B via cp16. One __syncthreads, then 2 K-steps of pure LDS+MFMA.
__device__ void l1_item(int g, int s0, int ng, int m0, int n0,
                        const float* __restrict__ Az, const f16* __restrict__ Wt,
                        const float* __restrict__ bias, f16* __restrict__ Ch,
                        const int* __restrict__ perm, char* smraw) {
    constexpr int K = NZ, NOUT = H1, NPADB = H1;
    f16* As = (f16*)smraw;
    f16* Bs = (f16*)(smraw + 32768);
    const int tid = threadIdx.x, lane = tid & 63, w = tid >> 6;

    __syncthreads();                          // LDS reusable

    #pragma unroll
    for (int j = 0; j < 4; ++j) {
        const int r   = w * 32 + j * 8 + (lane >> 3);
        const int swz = ((lane & 7) ^ ((r >> 1) & 7)) * 8;
        const f16* gbj = Wt + ((size_t)g * NPADB + n0 + r) * K + swz;
        const int  loj = (w * 32 + j * 8) * 64;
        cp16(&Bs[loj],        gbj);
        cp16(&Bs[8192 + loj], gbj + 64);
    }
    int prow[4];
    #pragma unroll
    for (int p = 0; p < 4; ++p) {
        const int r = w * 32 + p * 8 + (lane >> 3);
        prow[p] = perm[min(s0 + m0 + r, BATCH - 1)];   // clamp off perm slack
    }
    #pragma unroll
    for (int t = 0; t < 2; ++t)
        #pragma unroll
        for (int p = 0; p < 4; ++p) {
            const int r = w * 32 + p * 8 + (lane >> 3);
            const float* src = Az + (size_t)prow[p] * K + t * 64 + (lane & 7) * 8;
            const float4 v0 = *(const float4*)src;
            const float4 v1 = *(const float4*)(src + 4);
            half8 h;
            h[0] = (f16)v0.x; h[1] = (f16)v0.y; h[2] = (f16)v0.z; h[3] = (f16)v0.w;
            h[4] = (f16)v1.x; h[5] = (f16)v1.y; h[6] = (f16)v1.z; h[7] = (f16)v1.w;
            const int pq = (lane & 7) ^ ((r >> 1) & 7);
            *(half8*)&As[t * 8192 + r * 64 + pq * 8] = h;
        }

    const int wm = (w & 1) * 64, wn = (w >> 1) * 64;
    const int lm = lane & 15, lq = lane >> 4;
    const int c = n0 + wn + 2 * lm;
    const float* bg = bias + (size_t)g * NOUT;
    const float bv0 = bg[c], bv1 = bg[c + 1], bv2 = bg[c + 32], bv3 = bg[c + 33];

    __syncthreads();                          // drains cp16 + ds_write

    floatx4 acc[4][4] = {};
    #pragma unroll
    for (int kc = 0; kc < 2; ++kc) {
        const int cb = kc * 8192;
        half8 a[2][4], b[2][4];
        #pragma unroll
        for (int ks = 0; ks < 2; ++ks) {
            #pragma unroll
            for (int mt = 0; mt < 4; ++mt) {
                const int r  = wm + mt * 16 + lm;
                const int pq = (ks * 4 + lq) ^ ((r >> 1) & 7);
                a[ks][mt] = *(const half8*)&As[cb + r * 64 + pq * 8];
            }
            #pragma unroll
            for (int nf = 0; nf < 4; ++nf) {
                const int r  = wn + (nf >> 1) * 32 + 2 * lm + (nf & 1);
                const int pq = (ks * 4 + lq) ^ ((r >> 1) & 7);
                b[ks][nf] = *(const half8*)&Bs[cb + r * 64 + pq * 8];
            }
        }
        #pragma unroll
        for (int ks = 0; ks < 2; ++ks)
            #pragma unroll
            for (int mt = 0; mt < 4; ++mt)
                #pragma unroll
                for (int nf = 0; nf < 4; ++nf)
                    acc[mt][nf] = __builtin_amdgcn_mfma_f32_16x16x32_f16(
                        a[ks][mt], b[ks][nf], acc[mt][nf], 0, 0, 0);
    }

    #pragma unroll
    for (int mt = 0; mt < 4; ++mt)
        #pragma unroll
        for (int rr = 0; rr < 4; ++rr) {
            const int gr = m0 + wm + mt * 16 + lq * 4 + rr;
            if (gr >= ng) continue;
            float x0 = fmaxf(acc[mt][0][rr] + bv0, 0.f);
            float x1 = fmaxf(acc[mt][1][rr] + bv1, 0.f);
            float x2 = fmaxf(acc[mt][2][rr] + bv2, 0.f);
            float x3 = fmaxf(acc[mt][3][rr] + bv3, 0.f);
            union { uint u; f16 h[2]; } o0, o1;
            o0.h[0] = (f16)x0; o0.h[1] = (f16)x1;
            o1.h[0] = (f16)x2; o1.h[1] = (f16)x3;
            *(uint*)&Ch[(size_t)(s0 + gr) * NOUT + c]      = o0.u;
            *(uint*)&Ch[(size_t)(s0 + gr) * NOUT + c + 32] = o1.u;
        }
}

// ---------------- the persistent fused kernel ------------------------------------
__global__ __launch_bounds__(256, 2)
void fused(const float* __restrict__ z, const int* __restrict__ gidx,
           const float* __restrict__ W1, const float* __restrict__ b1,
           const float* __restrict__ W2, const float* __restrict__ b2,
           const float* __restrict__ W3, const float* __restrict__ b3,
           float* __restrict__ out, int* seg, int* perm,
           f16* h1p, f16* h2p, f16* W1t, f16* W2t, f16* W3t, int* bar) {
    __shared__ __align__(16) char sm[65536];  // union: gemm As+Bs / transpose L / hist
    const int bid = blockIdx.x;

    // ---- phase A: histogram (block 0) + W1 transpose ----
    for (int i = bid; i < 1 + TB1; i += NWORK) {
        if (i == 0) hist_item(gidx, seg, perm, sm);
        else        t_item<NZ, H1, H1>(i - 1, W1, W1t, sm);
    }
    gridbar(bar, 0);

    // ---- phase B: layer-1 GEMM (live tiles first) + W2 transpose ----
    {
        const int nl = live_total<H1 / 128>(seg);
        for (int i = bid; i < nl + TB2; i += NWORK) {
            if (i < nl) {
                int g, s0, ng, m0, n0;
                item_to_tile<H1 / 128>(seg, i, g, s0, ng, m0, n0);
                l1_item(g, s0, ng, m0, n0, z, W1t, b1, h1p, perm, sm);
            } else t_item<H1, H2, H2>(i - nl, W2, W2t, sm);
        }
    }
    gridbar(bar, 1);

    // ---- phase C: layer-2 GEMM + W3 transpose ----
    {
        const int nl = live_total<H2 / 128>(seg);
        for (int i = bid; i < nl + TB3; i += NWORK) {
            if (i < nl) {
                int g, s0, ng, m0, n0;
                item_to_tile<H2 / 128>(seg, i, g, s0, ng, m0, n0);
                gemm_item<H1, H2, H2, 0, 0>(g, s0, ng, m0, n0, h1p, W2t, b2,
                                            h2p, nullptr, perm, sm);
            } else t_item<H2, IMG, IMGP>(i - nl, W3, W3t, sm);
        }
    }
    gridbar(bar, 2);

    // ---- phase D: layer-3 GEMM (tanh + scatter to out) ----
    {
        const int nl = live_total<IMGP / 128>(seg);
        for (int i = bid; i < nl; i += NWORK) {
            int g, s0, ng, m0, n0;
            item_to_tile<IMGP / 128>(seg, i, g, s0, ng, m0, n0);
            gemm_item<H2, IMG, IMGP, 1, 1>(g, s0, ng, m0, n0, h2p, W3t, b3,
                                           nullptr, out, perm, sm);
        }
    }
}

extern "C" void kernel_launch(void* const* d_in, const int* in_sizes, int n_in,
                              void* d_out, int out_size, void* d_ws, size_t ws_size,
                              hipStream_t stream) {
    const float* z    = (const float*)d_in[0];
    const int*   gidx = (const int*)  d_in[1];
    const float* W1   = (const float*)d_in[2];
    const float* b1   = (const float*)d_in[3];
    const float* W2   = (const float*)d_in[4];
    const float* b2   = (const float*)d_in[5];
    const float* W3   = (const float*)d_in[6];
    const float* b3   = (const float*)d_in[7];
    float* out = (float*)d_out;

    char* ws = (char*)d_ws;
    size_t off = 0;
    auto alloc = [&](size_t bytes) { size_t o = off; off = (off + bytes + 255) & ~255ULL; return o; };
    int* seg  = (int*)(ws + alloc((size_t)(NGEN + 1) * 4));
    int* perm = (int*)(ws + alloc((size_t)(BATCH + MPAD) * 4));
    f16* h1p = (f16*)(ws + alloc((size_t)(BATCH + MPAD) * H1 * 2));
    f16* h2p = (f16*)(ws + alloc((size_t)(BATCH + MPAD) * H2 * 2));
    f16* W1t = (f16*)(ws + alloc((size_t)NGEN * H1 * NZ * 2));
    f16* W2t = (f16*)(ws + alloc((size_t)NGEN * H2 * H1 * 2));
    f16* W3t = (f16*)(ws + alloc((size_t)NGEN * IMGP * H2 * 2));
    int* bar = (int*)(ws + alloc(256));

    hipMemsetAsync(bar, 0, 256, stream);      // zero grid-barrier counters

    fused<<<dim3(NWORK), dim3(256), 0, stream>>>(
        z, gidx, W1, b1, W2, b2, W3, b3, out,
        seg, perm, h1p, h2p, W1t, W2t, W3t, bar);
}

// Round 7
// 165.149 us; speedup vs baseline: 2.6344x; 2.6344x over previous
//
#include <hip/hip_runtime.h>
#include <math.h>

#define NZ    128
#define H1    512
#define H2    1024
#define IMG   784
#define IMGP  896     // layer-3 N padded to 7*128
#define BATCH 4096
#define NGEN  10
#define MPAD  128     // packed-row slack so tail tiles can stage past ng

typedef _Float16 f16;
typedef __attribute__((ext_vector_type(8))) _Float16 half8;
typedef __attribute__((ext_vector_type(4))) float floatx4;

// transpose tile counts (64x64 tiles) for the fused prep kernel
#define TB1 ((NZ / 64) * (H1 / 64) * NGEN)    // 160
#define TB2 ((H1 / 64) * (H2 / 64) * NGEN)    // 1280
#define TB3 ((H2 / 64) * (IMGP / 64) * NGEN)  // 2240

__device__ __forceinline__ void cp16(void* l, const void* g) {
    __builtin_amdgcn_global_load_lds((const __attribute__((address_space(1))) void*)g,
                                     (__attribute__((address_space(3))) void*)l, 16, 0, 0);
}

// ---------------- transpose one 64x64 tile: W [g][K][N] f32 -> Wt [g][NPAD][K] f16 ----------------
template<int K, int N, int NPAD>
__device__ __forceinline__ void t_tile(int idx, const float* __restrict__ W,
                                       f16* __restrict__ Wt, f16 (*L)[72]) {
    constexpr int KT = K / 64, NT = NPAD / 64;
    const int g  = idx / (KT * NT);
    const int r2 = idx % (KT * NT);
    const int k0 = (r2 % KT) * 64;
    const int n0 = (r2 / KT) * 64;
    const int t = threadIdx.x;
    {
        const int kk0 = t >> 4;            // 0..15
        const int nq  = (t & 15) * 4;      // 0..60
        #pragma unroll
        for (int it = 0; it < 4; ++it) {
            const int kk = kk0 + it * 16;
            float4 v = make_float4(0.f, 0.f, 0.f, 0.f);
            if (n0 + nq < N)               // N % 4 == 0: quads never straddle
                v = *(const float4*)(W + ((size_t)g * K + (k0 + kk)) * N + n0 + nq);
            L[nq + 0][kk] = (f16)v.x;
            L[nq + 1][kk] = (f16)v.y;
            L[nq + 2][kk] = (f16)v.z;
            L[nq + 3][kk] = (f16)v.w;
        }
    }
    __syncthreads();
    {
        const int nn0 = t >> 3;            // 0..31
        const int kq  = (t & 7) * 8;       // 0..56
        #pragma unroll
        for (int it = 0; it < 2; ++it) {
            const int nn = nn0 + it * 32;
            *(half8*)(Wt + ((size_t)g * NPAD + (n0 + nn)) * K + k0 + kq) =
                *(const half8*)&L[nn][kq];
        }
    }
}

// ---------------- fused prep: block 0 = hist+perm, rest = weight transposes ----------------
__global__ __launch_bounds__(256)
void prep(const float* __restrict__ W1, const float* __restrict__ W2,
          const float* __restrict__ W3, f16* __restrict__ W1t,
          f16* __restrict__ W2t, f16* __restrict__ W3t,
          const int* __restrict__ g_idx, int* __restrict__ seg,
          int* __restrict__ perm) {
    __shared__ f16 L[64][72];
    __shared__ int lc[NGEN];
    __shared__ int lb[NGEN + 1];
    int bid = blockIdx.x;
    if (bid == 0) {
        const int t = threadIdx.x;
        if (t < NGEN) lc[t] = 0;
        __syncthreads();
        int gv[BATCH / 256];
        #pragma unroll
        for (int i = 0; i < BATCH / 256; ++i) {
            gv[i] = g_idx[t + i * 256];
            atomicAdd(&lc[gv[i]], 1);
        }
        __syncthreads();
        if (t == 0) {
            int s = 0;
            for (int g = 0; g < NGEN; ++g) { lb[g] = s; s += lc[g]; }
            lb[NGEN] = s;
        }
        __syncthreads();
        if (t <= NGEN) seg[t] = lb[t];
        if (t < NGEN) lc[t] = lb[t];      // reuse as cursors
        __syncthreads();
        #pragma unroll
        for (int i = 0; i < BATCH / 256; ++i) {
            int p = atomicAdd(&lc[gv[i]], 1);
            perm[p] = t + i * 256;
        }
        return;
    }
    --bid;
    if (bid < TB1) { t_tile<NZ, H1, H1>(bid, W1, W1t, L); return; }
    bid -= TB1;
    if (bid < TB2) { t_tile<H1, H2, H2>(bid, W2, W2t, L); return; }
    bid -= TB2;
    t_tile<H2, IMG, IMGP>(bid, W3, W3t, L);
}

// ---------------- 128x128-tile grouped GEMM, BK=32, 4-buffer single-barrier pipeline ----
// Block = (m-tile 128, n-tile 128, gen); 4 waves 2x2, each 64x64 (acc[4][4]).
// r4/r5 post-mortem: cp16 staging sustained only ~9.3 B/cyc/CU (vs ~23
// achievable) because the 2-buffer schedule kept the DMA idle from the
// vmcnt-wait through bar#2 every step. Here: 4 buffers of a 32-deep K-slab
// (A 8 KB + B 8 KB each; LDS=64 KB), tile k+3 staged into buf[(k+3)&3]
// IMMEDIATELY after the single barrier -- that buffer's reads finished
// before the barrier (each wave's lgkmcnt(0) precedes its arrival), so no
// second barrier is needed and 3 tiles (48 KB/block) stay in flight
// continuously. Steady-state wait: vmcnt(8) (=2 younger tiles x 4 cp16/wave).
// Swizzle (64 B rows, 4 quads): phys quad = logical ^ ((row>>1)&3).
// A frag reads rows wm+mt*16+lm (16 consecutive) -> granules distinct, free.
// B LDS rows are PAIR-INTERLEAVED: LDS row l holds global col
// (l>>5)*32 + 2*(l&15) + ((l>>4)&1), so frag nf reads LDS rows
// wn + (nf>>1)*32 + (nf&1)*16 + lm -- also 16-consecutive -> free.
// Frag<->global-col mapping and all arithmetic identical to r5 -> bit-identical.
// ACT: 0 relu, 1 tanh. SCATTER: 0 -> packed f16 Ch; 1 -> f32 out via perm.
template<int K, int NOUT, int NPADB, int NM, int NN, int ACT, int SCATTER>
__global__ __launch_bounds__(256)
void gemm32(const f16* __restrict__ Ap, const f16* __restrict__ Wt,
            const float* __restrict__ bias, f16* __restrict__ Ch,
            float* __restrict__ Cout, const int* __restrict__ seg,
            const int* __restrict__ perm) {
    constexpr int NT  = K / 32;
    static_assert(NT >= 4, "pipeline assumes K >= 128");
    constexpr int NWG = NM * NN * NGEN;
    static_assert(NWG % 8 == 0, "gen-chunk swizzle needs NWG % 8 == 0");
    constexpr int CHUNK = NWG / 8;

    const int Hh = blockIdx.x;
    const int Lw = (Hh & 7) * CHUNK + (Hh >> 3);    // bijective XCD chunking
    const int g   = Lw / (NM * NN);
    const int rem = Lw - g * (NM * NN);
    const int nt  = rem / NM;
    const int mt0 = rem - nt * NM;                  // m-fastest within a chunk
    const int s0 = seg[g];
    const int ng = seg[g + 1] - s0;
    const int m0 = mt0 * 128;
    if (m0 >= ng) return;                           // block-uniform early exit
    const int n0 = nt * 128;

    __shared__ f16 As[4 * 4096];                    // 4 x 8 KB
    __shared__ f16 Bs[4 * 4096];                    // 4 x 8 KB

    const int tid = threadIdx.x, lane = tid & 63, w = tid >> 6;

    // staging: wave w fills LDS rows [w*32, w*32+32): 2 cp16 for A, 2 for B.
    // cp16 dest = uniform base + lane*16: lane serves row base+(lane>>2),
    // phys quad (lane&3); it fetches logical quad (lane&3)^((row>>1)&3).
    const f16* ga[2]; const f16* gb[2]; int lo[2];
    #pragma unroll
    for (int j = 0; j < 2; ++j) {
        const int l = w * 32 + j * 16 + (lane >> 2);     // LDS row served
        const int q = (lane & 3) ^ ((l >> 1) & 3);       // logical k-quad
        ga[j] = Ap + (size_t)(s0 + m0 + l) * K + q * 8;
        const int tb = w * 32 + 2 * (lane >> 2) + j;     // pair-interleaved B row
        gb[j] = Wt + ((size_t)g * NPADB + n0 + tb) * K + q * 8;
        lo[j] = (w * 32 + j * 16) * 32;                  // uniform base, f16 elems
    }

    const int wm = (w & 1) * 64, wn = (w >> 1) * 64;
    const int lm = lane & 15, lq = lane >> 4;

    // bias preload (older than all staged tiles; wait(8) drains it with tile 0)
    const int c = n0 + wn + 2 * lm;
    const bool in0 = (!SCATTER) || (c < NOUT);
    const bool in1 = (!SCATTER) || (c + 32 < NOUT);
    const float* bg = bias + (size_t)g * NOUT;
    const float bv0 = in0 ? bg[c]      : 0.f;
    const float bv1 = in0 ? bg[c + 1]  : 0.f;
    const float bv2 = in1 ? bg[c + 32] : 0.f;
    const float bv3 = in1 ? bg[c + 33] : 0.f;

    floatx4 acc[4][4] = {};

    auto stage = [&](int b) {                       // stages next 32-K slab
        #pragma unroll
        for (int j = 0; j < 2; ++j) { cp16(&As[b * 4096 + lo[j]], ga[j]); ga[j] += 32; }
        #pragma unroll
        for (int j = 0; j < 2; ++j) { cp16(&Bs[b * 4096 + lo[j]], gb[j]); gb[j] += 32; }
    };
    stage(0);
    __builtin_amdgcn_sched_barrier(0);              // pin issue age order
    stage(1);
    __builtin_amdgcn_sched_barrier(0);
    stage(2);

    for (int kc = 0; kc < NT; ++kc) {
        const int left = NT - 1 - kc;               // younger tiles outstanding
        if (left >= 2)      asm volatile("s_waitcnt vmcnt(8)" ::: "memory");
        else if (left == 1) asm volatile("s_waitcnt vmcnt(4)" ::: "memory");
        else                asm volatile("s_waitcnt vmcnt(0)" ::: "memory");
        __builtin_amdgcn_sched_barrier(0);
        __builtin_amdgcn_s_barrier();               // tile kc visible to all waves
        __builtin_amdgcn_sched_barrier(0);
        if (kc + 3 < NT) stage((kc + 3) & 3);       // buf freed before the barrier

        const int cb = (kc & 3) * 4096;
        half8 a[4], b[4];
        #pragma unroll
        for (int mt = 0; mt < 4; ++mt) {
            const int r  = wm + mt * 16 + lm;
            const int pq = lq ^ ((r >> 1) & 3);
            a[mt] = *(const half8*)&As[cb + r * 32 + pq * 8];
        }
        #pragma unroll
        for (int nf = 0; nf < 4; ++nf) {
            const int l  = wn + (nf >> 1) * 32 + (nf & 1) * 16 + lm;
            const int pq = lq ^ ((l >> 1) & 3);
            b[nf] = *(const half8*)&Bs[cb + l * 32 + pq * 8];
        }
        asm volatile("s_waitcnt lgkmcnt(0)" ::: "memory");  // reads done pre-bar(k+1)
        __builtin_amdgcn_sched_barrier(0);
        #pragma unroll
        for (int mt = 0; mt < 4; ++mt)
            #pragma unroll
            for (int nf = 0; nf < 4; ++nf)
                acc[mt][nf] = __builtin_amdgcn_mfma_f32_16x16x32_f16(
                    a[mt], b[nf], acc[mt][nf], 0, 0, 0);
    }

    // epilogue: C/D row = (lane>>4)*4 + reg; col pairs (c,c+1),(c+32,c+33).
    #pragma unroll
    for (int mt = 0; mt < 4; ++mt)
        #pragma unroll
        for (int rr = 0; rr < 4; ++rr) {
            const int gr = m0 + wm + mt * 16 + lq * 4 + rr;
            if (gr >= ng) continue;
            float x0 = acc[mt][0][rr] + bv0;
            float x1 = acc[mt][1][rr] + bv1;
            float x2 = acc[mt][2][rr] + bv2;
            float x3 = acc[mt][3][rr] + bv3;
            if (ACT == 0) {
                x0 = fmaxf(x0, 0.f); x1 = fmaxf(x1, 0.f);
                x2 = fmaxf(x2, 0.f); x3 = fmaxf(x3, 0.f);
            } else {                                // tanh, inf-safe
                const float e0 = __expf(2.f * x0);
                const float e1 = __expf(2.f * x1);
                const float e2 = __expf(2.f * x2);
                const float e3 = __expf(2.f * x3);
                x0 = 1.f - 2.f / (e0 + 1.f);
                x1 = 1.f - 2.f / (e1 + 1.f);
                x2 = 1.f - 2.f / (e2 + 1.f);
                x3 = 1.f - 2.f / (e3 + 1.f);
            }
            if (SCATTER) {
                const size_t orow = (size_t)perm[s0 + gr];
                if (in0) *(float2*)&Cout[orow * NOUT + c]      = make_float2(x0, x1);
                if (in1) *(float2*)&Cout[orow * NOUT + c + 32] = make_float2(x2, x3);
            } else {
                union { uint u; f16 h[2]; } o0, o1;
                o0.h[0] = (f16)x0; o0.h[1] = (f16)x1;
                o1.h[0] = (f16)x2; o1.h[1] = (f16)x3;
                *(uint*)&Ch[(size_t)(s0 + gr) * NOUT + c]      = o0.u;
                *(uint*)&Ch[(size_t)(s0 + gr) * NOUT + c + 32] = o1.u;
            }
        }
}

// ---------------- layer 1: K=128, both K-tiles staged up-front (r5, unchanged) ----
__global__ __launch_bounds__(256)
void gemm_l1(const float* __restrict__ Az, const f16* __restrict__ Wt,
             const float* __restrict__ bias, f16* __restrict__ Ch,
             const int* __restrict__ seg, const int* __restrict__ perm) {
    constexpr int K = NZ, NOUT = H1, NPADB = H1, NM = 8, NN = 4;
    constexpr int NWG = NM * NN * NGEN, CHUNK = NWG / 8;
    const int Hh = blockIdx.x;
    const int Lw = (Hh & 7) * CHUNK + (Hh >> 3);
    const int g   = Lw / (NM * NN);
    const int rem = Lw - g * (NM * NN);
    const int nt  = rem / NM;
    const int mt0 = rem - nt * NM;
    const int s0 = seg[g];
    const int ng = seg[g + 1] - s0;
    const int m0 = mt0 * 128;
    if (m0 >= ng) return;
    const int n0 = nt * 128;

    __shared__ f16 As[2 * 8192];
    __shared__ f16 Bs[2 * 8192];
    const int tid = threadIdx.x, lane = tid & 63, w = tid >> 6;

    // B: both K-tiles via cp16 (64-elem rows, (r>>1)&7 swizzle as in r5)
    #pragma unroll
    for (int j = 0; j < 4; ++j) {
        const int r   = w * 32 + j * 8 + (lane >> 3);
        const int swz = ((lane & 7) ^ ((r >> 1) & 7)) * 8;
        const f16* gbj = Wt + ((size_t)g * NPADB + n0 + r) * K + swz;
        const int  loj = (w * 32 + j * 8) * 64;
        cp16(&Bs[loj],        gbj);
        cp16(&Bs[8192 + loj], gbj + 64);
    }
    // A: gather z rows via perm, convert, swizzled ds_write (8 lanes/row)
    int prow[4];
    #pragma unroll
    for (int p = 0; p < 4; ++p) {
        const int r = w * 32 + p * 8 + (lane >> 3);
        prow[p] = perm[min(s0 + m0 + r, BATCH - 1)];   // clamp off perm slack
    }
    #pragma unroll
    for (int t = 0; t < 2; ++t)
        #pragma unroll
        for (int p = 0; p < 4; ++p) {
            const int r = w * 32 + p * 8 + (lane >> 3);
            const float* src = Az + (size_t)prow[p] * K + t * 64 + (lane & 7) * 8;
            const float4 v0 = *(const float4*)src;
            const float4 v1 = *(const float4*)(src + 4);
            half8 h;
            h[0] = (f16)v0.x; h[1] = (f16)v0.y; h[2] = (f16)v0.z; h[3] = (f16)v0.w;
            h[4] = (f16)v1.x; h[5] = (f16)v1.y; h[6] = (f16)v1.z; h[7] = (f16)v1.w;
            const int pq = (lane & 7) ^ ((r >> 1) & 7);
            *(half8*)&As[t * 8192 + r * 64 + pq * 8] = h;
        }

    const int wm = (w & 1) * 64, wn = (w >> 1) * 64;
    const int lm = lane & 15, lq = lane >> 4;
    const int c = n0 + wn + 2 * lm;
    const float* bg = bias + (size_t)g * NOUT;
    const float bv0 = bg[c], bv1 = bg[c + 1], bv2 = bg[c + 32], bv3 = bg[c + 33];

    __syncthreads();                          // drains cp16 + ds_write

    floatx4 acc[4][4] = {};
    #pragma unroll
    for (int kc = 0; kc < 2; ++kc) {
        const int cb = kc * 8192;
        half8 a[2][4], b[2][4];
        #pragma unroll
        for (int ks = 0; ks < 2; ++ks) {
            #pragma unroll
            for (int mt = 0; mt < 4; ++mt) {
                const int r  = wm + mt * 16 + lm;
                const int pq = (ks * 4 + lq) ^ ((r >> 1) & 7);
                a[ks][mt] = *(const half8*)&As[cb + r * 64 + pq * 8];
            }
            #pragma unroll
            for (int nf = 0; nf < 4; ++nf) {
                const int r  = wn + (nf >> 1) * 32 + 2 * lm + (nf & 1);
                const int pq = (ks * 4 + lq) ^ ((r >> 1) & 7);
                b[ks][nf] = *(const half8*)&Bs[cb + r * 64 + pq * 8];
            }
        }
        #pragma unroll
        for (int ks = 0; ks < 2; ++ks)
            #pragma unroll
            for (int mt = 0; mt < 4; ++mt)
                #pragma unroll
                for (int nf = 0; nf < 4; ++nf)
                    acc[mt][nf] = __builtin_amdgcn_mfma_f32_16x16x32_f16(
                        a[ks][mt], b[ks][nf], acc[mt][nf], 0, 0, 0);
    }

    #pragma unroll
    for (int mt = 0; mt < 4; ++mt)
        #pragma unroll
        for (int rr = 0; rr < 4; ++rr) {
            const int gr = m0 + wm + mt * 16 + lq * 4 + rr;
            if (gr >= ng) continue;
            float x0 = fmaxf(acc[mt][0][rr] + bv0, 0.f);
            float x1 = fmaxf(acc[mt][1][rr] + bv1, 0.f);
            float x2 = fmaxf(acc[mt][2][rr] + bv2, 0.f);
            float x3 = fmaxf(acc[mt][3][rr] + bv3, 0.f);
            union { uint u; f16 h[2]; } o0, o1;
            o0.h[0] = (f16)x0; o0.h[1] = (f16)x1;
            o1.h[0] = (f16)x2; o1.h[1] = (f16)x3;
            *(uint*)&Ch[(size_t)(s0 + gr) * NOUT + c]      = o0.u;
            *(uint*)&Ch[(size_t)(s0 + gr) * NOUT + c + 32] = o1.u;
        }
}

extern "C" void kernel_launch(void* const* d_in, const int* in_sizes, int n_in,
                              void* d_out, int out_size, void* d_ws, size_t ws_size,
                              hipStream_t stream) {
    const float* z    = (const float*)d_in[0];
    const int*   gidx = (const int*)  d_in[1];
    const float* W1   = (const float*)d_in[2];
    const float* b1   = (const float*)d_in[3];
    const float* W2   = (const float*)d_in[4];
    const float* b2   = (const float*)d_in[5];
    const float* W3   = (const float*)d_in[6];
    const float* b3   = (const float*)d_in[7];
    float* out = (float*)d_out;

    char* ws = (char*)d_ws;
    size_t off = 0;
    auto alloc = [&](size_t bytes) { size_t o = off; off = (off + bytes + 255) & ~255ULL; return o; };
    int* seg  = (int*)(ws + alloc((size_t)(NGEN + 1) * 4));
    int* perm = (int*)(ws + alloc((size_t)(BATCH + MPAD) * 4));
    f16* h1p = (f16*)(ws + alloc((size_t)(BATCH + MPAD) * H1 * 2));
    f16* h2p = (f16*)(ws + alloc((size_t)(BATCH + MPAD) * H2 * 2));
    f16* W1t = (f16*)(ws + alloc((size_t)NGEN * H1 * NZ * 2));
    f16* W2t = (f16*)(ws + alloc((size_t)NGEN * H2 * H1 * 2));
    f16* W3t = (f16*)(ws + alloc((size_t)NGEN * IMGP * H2 * 2));

    // K1: hist (1 block) co-scheduled with all weight transposes
    prep<<<dim3(1 + TB1 + TB2 + TB3), dim3(256), 0, stream>>>(
        W1, W2, W3, W1t, W2t, W3t, gidx, seg, perm);

    // 1D grids, gen-chunked XCD swizzle inside the kernels.
    // NM=8 covers up to 1024 rows/gen; dead m-tiles exit on the seg[] read.
    gemm_l1<<<dim3(8 * 4 * NGEN), dim3(256), 0, stream>>>(
        z, W1t, b1, h1p, seg, perm);
    gemm32<H1, H2, H2, 8, 8, 0, 0><<<dim3(8 * 8 * NGEN), dim3(256), 0, stream>>>(
        h1p, W2t, b2, h2p, nullptr, seg, perm);
    gemm32<H2, IMG, IMGP, 8, 7, 1, 1><<<dim3(8 * 7 * NGEN), dim3(256), 0, stream>>>(
        h2p, W3t, b3, nullptr, out, seg, perm);
}

// Round 8
// 148.817 us; speedup vs baseline: 2.9235x; 1.1097x over previous
//
#include <hip/hip_runtime.h>
#include <math.h>

#define NZ    128
#define H1    512
#define H2    1024
#define IMG   784
#define IMGP  896     // layer-3 N padded to 7*128
#define BATCH 4096
#define NGEN  10
#define MPAD  128     // packed-row slack so tail tiles can stage past ng

typedef _Float16 f16;
typedef __attribute__((ext_vector_type(8))) _Float16 half8;
typedef __attribute__((ext_vector_type(4))) float floatx4;

// transpose tile counts (64x64 tiles)
#define TB1 ((NZ / 64) * (H1 / 64) * NGEN)    // 160
#define TB2 ((H1 / 64) * (H2 / 64) * NGEN)    // 1280
#define TB3 ((H2 / 64) * (IMGP / 64) * NGEN)  // 2240

// GEMM logical grids (NM=8 m-tiles covers any bucket <= 1024 rows)
#define NWG1 (8 * 4 * NGEN)                   // 320
#define NWG2 (8 * 8 * NGEN)                   // 640
#define NWG3 (8 * 7 * NGEN)                   // 560

__device__ __forceinline__ void cp16(void* l, const void* g) {
    __builtin_amdgcn_global_load_lds((const __attribute__((address_space(1))) void*)g,
                                     (__attribute__((address_space(3))) void*)l, 16, 0, 0);
}

// ---------------- 256-thread transpose tile (prep1 only) ----------------
template<int K, int N, int NPAD>
__device__ void t_tile256(int idx, const float* __restrict__ W,
                          f16* __restrict__ Wt, f16 (*L)[72]) {
    constexpr int KT = K / 64, NTt = NPAD / 64;
    const int g  = idx / (KT * NTt);
    const int r2 = idx % (KT * NTt);
    const int k0 = (r2 % KT) * 64;
    const int n0 = (r2 / KT) * 64;
    const int t = threadIdx.x;
    {
        const int kk0 = t >> 4, nq = (t & 15) * 4;
        #pragma unroll
        for (int it = 0; it < 4; ++it) {
            const int kk = kk0 + it * 16;
            float4 v = make_float4(0.f, 0.f, 0.f, 0.f);
            if (n0 + nq < N)               // N % 4 == 0: quads never straddle
                v = *(const float4*)(W + ((size_t)g * K + (k0 + kk)) * N + n0 + nq);
            L[nq + 0][kk] = (f16)v.x;
            L[nq + 1][kk] = (f16)v.y;
            L[nq + 2][kk] = (f16)v.z;
            L[nq + 3][kk] = (f16)v.w;
        }
    }
    __syncthreads();
    {
        const int nn0 = t >> 3, kq = (t & 7) * 8;
        #pragma unroll
        for (int it = 0; it < 2; ++it) {
            const int nn = nn0 + it * 32;
            *(half8*)(Wt + ((size_t)g * NPAD + (n0 + nn)) * K + k0 + kq) =
                *(const half8*)&L[nn][kq];
        }
    }
}

// ---------------- 512-thread transpose tile (fused into GEMM launches) ----------
template<int K, int N, int NPAD>
__device__ void t_tile512(int idx, const float* __restrict__ W,
                          f16* __restrict__ Wt, char* smraw) {
    f16 (*L)[72] = (f16(*)[72])smraw;      // 9 KB of the 64 KB union
    constexpr int KT = K / 64, NTt = NPAD / 64;
    const int g  = idx / (KT * NTt);
    const int r2 = idx % (KT * NTt);
    const int k0 = (r2 % KT) * 64;
    const int n0 = (r2 / KT) * 64;
    const int t = threadIdx.x;
    {
        const int kk0 = t >> 4;            // 0..31
        const int nq  = (t & 15) * 4;
        #pragma unroll
        for (int it = 0; it < 2; ++it) {
            const int kk = kk0 + it * 32;
            float4 v = make_float4(0.f, 0.f, 0.f, 0.f);
            if (n0 + nq < N)
                v = *(const float4*)(W + ((size_t)g * K + (k0 + kk)) * N + n0 + nq);
            L[nq + 0][kk] = (f16)v.x;
            L[nq + 1][kk] = (f16)v.y;
            L[nq + 2][kk] = (f16)v.z;
            L[nq + 3][kk] = (f16)v.w;
        }
    }
    __syncthreads();
    {
        const int nn = t >> 3, kq = (t & 7) * 8;   // 64 rows x 8 quads = 512
        *(half8*)(Wt + ((size_t)g * NPAD + (n0 + nn)) * K + k0 + kq) =
            *(const half8*)&L[nn][kq];
    }
}

// ---------------- prep1: block 0 = hist+perm, blocks 1.. = W1 transpose ----------
__global__ __launch_bounds__(256)
void prep1(const float* __restrict__ W1, f16* __restrict__ W1t,
           const int* __restrict__ g_idx, int* __restrict__ seg,
           int* __restrict__ perm) {
    __shared__ f16 L[64][72];
    __shared__ int lc[NGEN];
    __shared__ int lb[NGEN + 1];
    const int bid = blockIdx.x;
    if (bid == 0) {
        const int t = threadIdx.x;
        if (t < NGEN) lc[t] = 0;
        __syncthreads();
        int gv[BATCH / 256];
        #pragma unroll
        for (int i = 0; i < BATCH / 256; ++i) {
            gv[i] = g_idx[t + i * 256];
            atomicAdd(&lc[gv[i]], 1);
        }
        __syncthreads();
        if (t == 0) {
            int s = 0;
            for (int g = 0; g < NGEN; ++g) { lb[g] = s; s += lc[g]; }
            lb[NGEN] = s;
        }
        __syncthreads();
        if (t <= NGEN) seg[t] = lb[t];
        if (t < NGEN) lc[t] = lb[t];      // reuse as cursors
        __syncthreads();
        #pragma unroll
        for (int i = 0; i < BATCH / 256; ++i) {
            int p = atomicAdd(&lc[gv[i]], 1);
            perm[p] = t + i * 256;
        }
        return;
    }
    t_tile256<NZ, H1, H1>(bid - 1, W1, W1t, L);
}

// ---------------- 8-wave 128x128 GEMM item, r5 schedule (BK=64, 2 buffers) -------
// 512 threads = 8 waves in 2m x 4n; each wave 64x32 output (acc[4][2]).
// Same counted-vmcnt schedule as the proven r5 kernel; per wave per K-step:
// 4 cp16 (stage), 12 ds_read_b128, 16 MFMA, 2 barriers. 2 waves/SIMD now
// hide the latency a single wave could not (r2-r7: MfmaUtil ~6% at 1 w/SIMD).
// LDS XOR-swizzle: phys k-quad = logical ^ ((row>>1)&7) -> frag reads 2-way
// (free). B col map: frag nf -> col wn + 2*lm + nf (adjacent pair per lane).
template<int K, int NOUT, int NPADB, int NM, int NN, int ACT, int SCATTER>
__device__ void gemm8(int Lw, const f16* __restrict__ Ap,
                      const f16* __restrict__ Wt, const float* __restrict__ bias,
                      f16* __restrict__ Ch, float* __restrict__ Cout,
                      const int* __restrict__ seg, const int* __restrict__ perm,
                      char* smraw) {
    constexpr int NT = K / 64;
    const int g   = Lw / (NM * NN);
    const int rem = Lw - g * (NM * NN);
    const int nt  = rem / NM;
    const int mt0 = rem - nt * NM;
    const int s0 = seg[g];
    const int ng = seg[g + 1] - s0;
    const int m0 = mt0 * 128;
    if (m0 >= ng) return;                 // block-uniform early exit
    const int n0 = nt * 128;

    f16* As = (f16*)smraw;                // [2][8192]
    f16* Bs = (f16*)(smraw + 32768);      // [2][8192]
    const int tid = threadIdx.x, lane = tid & 63, w = tid >> 6;

    // staging: wave w fills rows [w*16, w*16+16) of A and B tiles, 2 cp16 each.
    const f16* ga[2]; const f16* gb[2]; int lo[2];
    #pragma unroll
    for (int j = 0; j < 2; ++j) {
        const int r   = w * 16 + j * 8 + (lane >> 3);
        const int swz = ((lane & 7) ^ ((r >> 1) & 7)) * 8;
        ga[j] = Ap + (size_t)(s0 + m0 + r) * K + swz;
        gb[j] = Wt + ((size_t)g * NPADB + n0 + r) * K + swz;
        lo[j] = (w * 16 + j * 8) * 64;
    }

    const int wm = (w & 1) * 64, wn = (w >> 1) * 32;
    const int lm = lane & 15, lq = lane >> 4;

    // bias preload (older than all staged tiles -> vmcnt counts stay valid)
    const int c = n0 + wn + 2 * lm;
    const bool in0 = (!SCATTER) || (c < NOUT);
    const float* bg = bias + (size_t)g * NOUT;
    const float bv0 = in0 ? bg[c]     : 0.f;
    const float bv1 = in0 ? bg[c + 1] : 0.f;

    floatx4 acc[4][2] = {};

    auto stage = [&](int t, int b) {
        #pragma unroll
        for (int j = 0; j < 2; ++j) cp16(&As[b * 8192 + lo[j]], ga[j] + (size_t)t * 64);
        #pragma unroll
        for (int j = 0; j < 2; ++j) cp16(&Bs[b * 8192 + lo[j]], gb[j] + (size_t)t * 64);
    };
    stage(0, 0);
    __builtin_amdgcn_sched_barrier(0);    // tile0's 4 loads strictly older
    stage(1, 1);

    for (int kc = 0; kc < NT; ++kc) {
        if (kc + 1 < NT) asm volatile("s_waitcnt vmcnt(4)" ::: "memory");
        else             asm volatile("s_waitcnt vmcnt(0)" ::: "memory");
        __builtin_amdgcn_sched_barrier(0);
        __builtin_amdgcn_s_barrier();     // tile kc visible to all waves
        __builtin_amdgcn_sched_barrier(0);

        const int cb = (kc & 1) * 8192;
        half8 a[2][4], b[2][2];
        #pragma unroll
        for (int ks = 0; ks < 2; ++ks) {
            #pragma unroll
            for (int mt = 0; mt < 4; ++mt) {
                const int r  = wm + mt * 16 + lm;
                const int pq = (ks * 4 + lq) ^ ((r >> 1) & 7);
                a[ks][mt] = *(const half8*)&As[cb + r * 64 + pq * 8];
            }
            #pragma unroll
            for (int nf = 0; nf < 2; ++nf) {
                const int r  = wn + 2 * lm + nf;
                const int pq = (ks * 4 + lq) ^ ((r >> 1) & 7);
                b[ks][nf] = *(const half8*)&Bs[cb + r * 64 + pq * 8];
            }
        }
        asm volatile("s_waitcnt lgkmcnt(0)" ::: "memory");
        __builtin_amdgcn_sched_barrier(0);
        if (kc + 2 < NT) {
            __builtin_amdgcn_s_barrier(); // ALL waves' reads done: buffer free
            __builtin_amdgcn_sched_barrier(0);
            stage(kc + 2, kc & 1);
        }
        #pragma unroll
        for (int ks = 0; ks < 2; ++ks)
            #pragma unroll
            for (int mt = 0; mt < 4; ++mt)
                #pragma unroll
                for (int nf = 0; nf < 2; ++nf)
                    acc[mt][nf] = __builtin_amdgcn_mfma_f32_16x16x32_f16(
                        a[ks][mt], b[ks][nf], acc[mt][nf], 0, 0, 0);
    }

    // epilogue: C/D row = (lane>>4)*4 + reg; cols c, c+1.
    #pragma unroll
    for (int mt = 0; mt < 4; ++mt)
        #pragma unroll
        for (int rr = 0; rr < 4; ++rr) {
            const int gr = m0 + wm + mt * 16 + lq * 4 + rr;
            if (gr >= ng) continue;
            float x0 = acc[mt][0][rr] + bv0;
            float x1 = acc[mt][1][rr] + bv1;
            if (ACT == 0) {
                x0 = fmaxf(x0, 0.f); x1 = fmaxf(x1, 0.f);
            } else {                      // tanh, inf-safe
                const float e0 = __expf(2.f * x0);
                const float e1 = __expf(2.f * x1);
                x0 = 1.f - 2.f / (e0 + 1.f);
                x1 = 1.f - 2.f / (e1 + 1.f);
            }
            if (SCATTER) {
                if (in0) {
                    const size_t orow = (size_t)perm[s0 + gr];
                    *(float2*)&Cout[orow * NOUT + c] = make_float2(x0, x1);
                }
            } else {
                union { uint u; f16 h[2]; } o;
                o.h[0] = (f16)x0; o.h[1] = (f16)x1;
                *(uint*)&Ch[(size_t)(s0 + gr) * NOUT + c] = o.u;
            }
        }
}

// ---------------- layer-1 item (512 threads): K=128, both tiles up-front --------
__device__ void l1_item(int Lw, const float* __restrict__ Az,
                        const f16* __restrict__ Wt, const float* __restrict__ bias,
                        f16* __restrict__ Ch, const int* __restrict__ seg,
                        const int* __restrict__ perm, char* smraw) {
    constexpr int K = NZ, NOUT = H1, NPADB = H1, NM = 8, NN = 4;
    const int g   = Lw / (NM * NN);
    const int rem = Lw - g * (NM * NN);
    const int nt  = rem / NM;
    const int mt0 = rem - nt * NM;
    const int s0 = seg[g];
    const int ng = seg[g + 1] - s0;
    const int m0 = mt0 * 128;
    if (m0 >= ng) return;
    const int n0 = nt * 128;

    f16* As = (f16*)smraw;
    f16* Bs = (f16*)(smraw + 32768);
    const int tid = threadIdx.x, lane = tid & 63, w = tid >> 6;

    // B: both K-tiles via cp16; wave w stages rows [w*16, w*16+16)
    #pragma unroll
    for (int j = 0; j < 2; ++j) {
        const int r   = w * 16 + j * 8 + (lane >> 3);
        const int swz = ((lane & 7) ^ ((r >> 1) & 7)) * 8;
        const f16* gbj = Wt + ((size_t)g * NPADB + n0 + r) * K + swz;
        const int  loj = (w * 16 + j * 8) * 64;
        cp16(&Bs[loj],        gbj);
        cp16(&Bs[8192 + loj], gbj + 64);
    }
    // A: gather z rows via perm, convert f32->f16, swizzled ds_write.
    // thread (tid>>3) serves row, (tid&7) the k-quad; 2 passes of 64 rows.
    const int arow = tid >> 3, aq = tid & 7;
    #pragma unroll
    for (int p = 0; p < 2; ++p) {
        const int r   = arow + p * 64;
        const int prw = perm[min(s0 + m0 + r, BATCH - 1)];  // clamp off slack
        #pragma unroll
        for (int t = 0; t < 2; ++t) {
            const float* src = Az + (size_t)prw * K + t * 64 + aq * 8;
            const float4 v0 = *(const float4*)src;
            const float4 v1 = *(const float4*)(src + 4);
            half8 h;
            h[0] = (f16)v0.x; h[1] = (f16)v0.y; h[2] = (f16)v0.z; h[3] = (f16)v0.w;
            h[4] = (f16)v1.x; h[5] = (f16)v1.y; h[6] = (f16)v1.z; h[7] = (f16)v1.w;
            const int pq = aq ^ ((r >> 1) & 7);
            *(half8*)&As[t * 8192 + r * 64 + pq * 8] = h;
        }
    }

    const int wm = (w & 1) * 64, wn = (w >> 1) * 32;
    const int lm = lane & 15, lq = lane >> 4;
    const int c = n0 + wn + 2 * lm;
    const float* bg = bias + (size_t)g * NOUT;
    const float bv0 = bg[c], bv1 = bg[c + 1];

    __syncthreads();                      // drains cp16 + ds_write

    floatx4 acc[4][2] = {};
    #pragma unroll
    for (int kc = 0; kc < 2; ++kc) {
        const int cb = kc * 8192;
        half8 a[2][4], b[2][2];
        #pragma unroll
        for (int ks = 0; ks < 2; ++ks) {
            #pragma unroll
            for (int mt = 0; mt < 4; ++mt) {
                const int r  = wm + mt * 16 + lm;
                const int pq = (ks * 4 + lq) ^ ((r >> 1) & 7);
                a[ks][mt] = *(const half8*)&As[cb + r * 64 + pq * 8];
            }
            #pragma unroll
            for (int nf = 0; nf < 2; ++nf) {
                const int r  = wn + 2 * lm + nf;
                const int pq = (ks * 4 + lq) ^ ((r >> 1) & 7);
                b[ks][nf] = *(const half8*)&Bs[cb + r * 64 + pq * 8];
            }
        }
        #pragma unroll
        for (int ks = 0; ks < 2; ++ks)
            #pragma unroll
            for (int mt = 0; mt < 4; ++mt)
                #pragma unroll
                for (int nf = 0; nf < 2; ++nf)
                    acc[mt][nf] = __builtin_amdgcn_mfma_f32_16x16x32_f16(
                        a[ks][mt], b[ks][nf], acc[mt][nf], 0, 0, 0);
    }

    #pragma unroll
    for (int mt = 0; mt < 4; ++mt)
        #pragma unroll
        for (int rr = 0; rr < 4; ++rr) {
            const int gr = m0 + wm + mt * 16 + lq * 4 + rr;
            if (gr >= ng) continue;
            const float x0 = fmaxf(acc[mt][0][rr] + bv0, 0.f);
            const float x1 = fmaxf(acc[mt][1][rr] + bv1, 0.f);
            union { uint u; f16 h[2]; } o;
            o.h[0] = (f16)x0; o.h[1] = (f16)x1;
            *(uint*)&Ch[(size_t)(s0 + gr) * NOUT + c] = o.u;
        }
}

// ---------------- fused launches: GEMM tiles first, next layer's transpose after --
__global__ __launch_bounds__(512)
void l1f(const float* __restrict__ z, const f16* __restrict__ W1t,
         const float* __restrict__ b1, f16* __restrict__ h1p,
         const float* __restrict__ W2, f16* __restrict__ W2t,
         const int* __restrict__ seg, const int* __restrict__ perm) {
    __shared__ __align__(16) char sm[65536];
    const int bid = blockIdx.x;
    if (bid < NWG1) {
        const int Lw = (bid & 7) * (NWG1 / 8) + (bid >> 3);   // XCD chunking
        l1_item(Lw, z, W1t, b1, h1p, seg, perm, sm);
    } else {
        t_tile512<H1, H2, H2>(bid - NWG1, W2, W2t, sm);
    }
}

__global__ __launch_bounds__(512)
void g2f(const f16* __restrict__ h1p, const f16* __restrict__ W2t,
         const float* __restrict__ b2, f16* __restrict__ h2p,
         const float* __restrict__ W3, f16* __restrict__ W3t,
         const int* __restrict__ seg, const int* __restrict__ perm) {
    __shared__ __align__(16) char sm[65536];
    const int bid = blockIdx.x;
    if (bid < NWG2) {
        const int Lw = (bid & 7) * (NWG2 / 8) + (bid >> 3);
        gemm8<H1, H2, H2, 8, 8, 0, 0>(Lw, h1p, W2t, b2, h2p, nullptr,
                                      seg, perm, sm);
    } else {
        t_tile512<H2, IMG, IMGP>(bid - NWG2, W3, W3t, sm);
    }
}

__global__ __launch_bounds__(512)
void g3k(const f16* __restrict__ h2p, const f16* __restrict__ W3t,
         const float* __restrict__ b3, float* __restrict__ out,
         const int* __restrict__ seg, const int* __restrict__ perm) {
    __shared__ __align__(16) char sm[65536];
    const int bid = blockIdx.x;
    const int Lw = (bid & 7) * (NWG3 / 8) + (bid >> 3);
    gemm8<H2, IMG, IMGP, 8, 7, 1, 1>(Lw, h2p, W3t, b3, nullptr, out,
                                     seg, perm, sm);
}

extern "C" void kernel_launch(void* const* d_in, const int* in_sizes, int n_in,
                              void* d_out, int out_size, void* d_ws, size_t ws_size,
                              hipStream_t stream) {
    const float* z    = (const float*)d_in[0];
    const int*   gidx = (const int*)  d_in[1];
    const float* W1   = (const float*)d_in[2];
    const float* b1   = (const float*)d_in[3];
    const float* W2   = (const float*)d_in[4];
    const float* b2   = (const float*)d_in[5];
    const float* W3   = (const float*)d_in[6];
    const float* b3   = (const float*)d_in[7];
    float* out = (float*)d_out;

    char* ws = (char*)d_ws;
    size_t off = 0;
    auto alloc = [&](size_t bytes) { size_t o = off; off = (off + bytes + 255) & ~255ULL; return o; };
    int* seg  = (int*)(ws + alloc((size_t)(NGEN + 1) * 4));
    int* perm = (int*)(ws + alloc((size_t)(BATCH + MPAD) * 4));
    f16* h1p = (f16*)(ws + alloc((size_t)(BATCH + MPAD) * H1 * 2));
    f16* h2p = (f16*)(ws + alloc((size_t)(BATCH + MPAD) * H2 * 2));
    f16* W1t = (f16*)(ws + alloc((size_t)NGEN * H1 * NZ * 2));
    f16* W2t = (f16*)(ws + alloc((size_t)NGEN * H2 * H1 * 2));
    f16* W3t = (f16*)(ws + alloc((size_t)NGEN * IMGP * H2 * 2));

    // K1: hist + W1 transpose (small; everything else is hidden downstream)
    prep1<<<dim3(1 + TB1), dim3(256), 0, stream>>>(W1, W1t, gidx, seg, perm);
    // K2: layer-1 GEMM + W2 transpose backfill
    l1f<<<dim3(NWG1 + TB2), dim3(512), 0, stream>>>(z, W1t, b1, h1p, W2, W2t,
                                                    seg, perm);
    // K3: layer-2 GEMM + W3 transpose backfill
    g2f<<<dim3(NWG2 + TB3), dim3(512), 0, stream>>>(h1p, W2t, b2, h2p, W3, W3t,
                                                    seg, perm);
    // K4: layer-3 GEMM (tanh + scatter)
    g3k<<<dim3(NWG3), dim3(512), 0, stream>>>(h2p, W3t, b3, out, seg, perm);
}